// Round 8
// baseline (142.787 us; speedup 1.0000x reference)
//
#include <hip/hip_runtime.h>
#include <math.h>

#define T_TOK 32768
#define DIM   2048
#define E_N   64
#define KP    2048   // padded reduction length (row 0 of Wt is zero)

// ws layout (floats): [0, 131072) Wt[2048][64]; [131072, +32768*64) logitsT[64][T]
#define WS_WT_FLOATS (KP * E_N)

typedef float v4f __attribute__((ext_vector_type(4)));

// ---------------- kernel 0: shift/pad + transpose weight -> Wt[k][e] ----------------
__global__ __launch_bounds__(256) void k_padw(const float* __restrict__ w,
                                              float* __restrict__ wt) {
  int idx = blockIdx.x * 256 + threadIdx.x;   // 0 .. 2048*64-1
  int k = idx >> 6;
  int e = idx & 63;
  wt[idx] = (k == 0) ? 0.f : w[e * 2047 + (k - 1)];
}

// ---------------- kernel 1: logitsT = (x[:,1:] @ W^T)^T ----------------
// Row-per-lane, weights-in-SGPR, 2 ROWS PER LANE (halves scalar-path traffic:
// one 64-float W chunk feeds 128 FMAs). Block = 128 rows, 8 waves; wave w owns
// k in [w*256, (w+1)*256) for BOTH row halves. Grid 256 = 1 block/CU.
// Reduce in two row-half phases through one 64 KB LDS buffer; per-row
// summation tree identical to the R7-passing kernel.
__global__ __launch_bounds__(512, 2) void k_logits(const float* __restrict__ x,
                                                   const float* __restrict__ wt,
                                                   float* __restrict__ logitsT) {
  __shared__ float buf[4][E_N][64];   // 64 KB
  const int tid  = threadIdx.x;
  const int lane = tid & 63;
  const int wv   = __builtin_amdgcn_readfirstlane(tid >> 6);  // 0..7 (SGPR)
  const int kbase = wv * 256;
  const int rowA = blockIdx.x * 128 + lane;   // rows 0..63 of block
  // rowB = rowA + 64                          // rows 64..127 of block

  const float* xpA = x + (size_t)rowA * DIM + kbase;          // per-lane
  const float* xpB = xpA + (size_t)64 * DIM;
  const float* wkbase = wt + (size_t)kbase * E_N;             // wave-uniform (SGPR)

  float accA[E_N], accB[E_N];
#pragma unroll
  for (int e = 0; e < E_N; ++e) { accA[e] = 0.f; accB[e] = 0.f; }

  for (int g = 0; g < 16; ++g) {       // 16 groups x 16 k = 256 k per wave
    v4f xa[4], xb[4];
#pragma unroll
    for (int q = 0; q < 4; ++q) {
      xa[q] = *(const v4f*)(xpA + q * 4);
      xb[q] = *(const v4f*)(xpB + q * 4);
    }
    const float* wk = wkbase + g * 16 * E_N;   // uniform
#pragma unroll
    for (int q = 0; q < 4; ++q) {
#pragma unroll
      for (int kk = 0; kk < 4; ++kk) {
        const float xkA = xa[q][kk];
        const float xkB = xb[q][kk];
        const float* wrow = wk + (q * 4 + kk) * E_N;   // uniform -> s_load
#pragma unroll
        for (int e = 0; e < E_N; ++e) {
          const float we = wrow[e];
          accA[e] = fmaf(xkA, we, accA[e]);
          accB[e] = fmaf(xkB, we, accB[e]);
        }
      }
    }
    xpA += 16; xpB += 16;
  }

  // ---- reduce phase 0: rows blk*128 + 0..63 (accA) ----
  if (wv < 4) {
#pragma unroll
    for (int e = 0; e < E_N; ++e) buf[wv][e][lane] = accA[e];
  }
  __syncthreads();
  if (wv >= 4) {
#pragma unroll
    for (int e = 0; e < E_N; ++e) buf[wv - 4][e][lane] += accA[e];
  }
  __syncthreads();
  {
    const int r  = tid & 63;
    const int e0 = (tid >> 6) * 8;
#pragma unroll
    for (int i = 0; i < 8; ++i) {
      const int e = e0 + i;
      const float v = ((buf[0][e][r] + buf[1][e][r]) + buf[2][e][r]) + buf[3][e][r];
      logitsT[(size_t)e * T_TOK + blockIdx.x * 128 + r] = v;
    }
  }
  __syncthreads();   // buf reuse

  // ---- reduce phase 1: rows blk*128 + 64..127 (accB) ----
  if (wv < 4) {
#pragma unroll
    for (int e = 0; e < E_N; ++e) buf[wv][e][lane] = accB[e];
  }
  __syncthreads();
  if (wv >= 4) {
#pragma unroll
    for (int e = 0; e < E_N; ++e) buf[wv - 4][e][lane] += accB[e];
  }
  __syncthreads();
  {
    const int r  = tid & 63;
    const int e0 = (tid >> 6) * 8;
#pragma unroll
    for (int i = 0; i < 8; ++i) {
      const int e = e0 + i;
      const float v = ((buf[0][e][r] + buf[1][e][r]) + buf[2][e][r]) + buf[3][e][r];
      logitsT[(size_t)e * T_TOK + blockIdx.x * 128 + 64 + r] = v;
    }
  }
}

// ---------------- kernel 2: per-row group-limited top-k routing ----------------
__global__ __launch_bounds__(256) void k_route(const float* __restrict__ logitsT,
                                               const float* __restrict__ bias,
                                               float* __restrict__ out_w,
                                               float* __restrict__ out_i) {
  __shared__ float bl[E_N];
  if (threadIdx.x < E_N) bl[threadIdx.x] = bias[threadIdx.x];
  __syncthreads();

  const int row = blockIdx.x * 256 + threadIdx.x;      // grid sized exactly
  const float* lp = logitsT + row;                     // column access: lane-coalesced

  float sb[E_N];                                       // sigmoid(logit) + bias
#pragma unroll
  for (int e = 0; e < E_N; ++e)
    sb[e] = 1.f / (1.f + expf(-lp[(size_t)e * T_TOK])) + bl[e];

  // group scores: sum of top-2 per group of 8
  float gs[8];
#pragma unroll
  for (int g = 0; g < 8; ++g) {
    float m1 = -__builtin_inff(), m2 = -__builtin_inff();
#pragma unroll
    for (int j = 0; j < 8; ++j) {
      float v = sb[g * 8 + j];
      if (v > m1) { m2 = m1; m1 = v; }
      else if (v > m2) { m2 = v; }
    }
    gs[g] = m1 + m2;
  }

  // top-4 groups (strict > : lower index wins ties, matches lax.top_k)
  unsigned gmask = 0;
#pragma unroll
  for (int tsel = 0; tsel < 4; ++tsel) {
    float best = -__builtin_inff(); int bi = 0;
#pragma unroll
    for (int g = 0; g < 8; ++g) {
      bool avail = ((gmask >> g) & 1u) == 0u;
      if (avail && gs[g] > best) { best = gs[g]; bi = g; }
    }
    gmask |= (1u << bi);
  }

  // taken-mask: pre-ban experts in dropped groups
  unsigned long long tm = 0ull;
#pragma unroll
  for (int g = 0; g < 8; ++g)
    if (((gmask >> g) & 1u) == 0u) tm |= (0xFFull << (8 * g));

  // top-8 experts over allowed groups
  float wv[8]; int io[8]; float wsum = 0.f;
#pragma unroll
  for (int tsel = 0; tsel < 8; ++tsel) {
    float best = -__builtin_inff(); int bi = 0;
#pragma unroll
    for (int e = 0; e < E_N; ++e) {
      bool avail = ((tm >> e) & 1ull) == 0ull;
      if (avail && sb[e] > best) { best = sb[e]; bi = e; }
    }
    tm |= (1ull << bi);
    float sv = best - bl[bi];        // original sigmoid score (bias removed)
    wv[tsel] = sv; io[tsel] = bi; wsum += sv;
  }

  const float scale = 2.5f / wsum;
  float4 w0 = make_float4(wv[0] * scale, wv[1] * scale, wv[2] * scale, wv[3] * scale);
  float4 w1 = make_float4(wv[4] * scale, wv[5] * scale, wv[6] * scale, wv[7] * scale);
  float4 i0 = make_float4((float)io[0], (float)io[1], (float)io[2], (float)io[3]);
  float4 i1 = make_float4((float)io[4], (float)io[5], (float)io[6], (float)io[7]);
  *(float4*)(out_w + (size_t)row * 8)     = w0;
  *(float4*)(out_w + (size_t)row * 8 + 4) = w1;
  *(float4*)(out_i + (size_t)row * 8)     = i0;
  *(float4*)(out_i + (size_t)row * 8 + 4) = i1;
}

extern "C" void kernel_launch(void* const* d_in, const int* in_sizes, int n_in,
                              void* d_out, int out_size, void* d_ws, size_t ws_size,
                              hipStream_t stream) {
  const float* x    = (const float*)d_in[0];
  const float* wgt  = (const float*)d_in[1];
  const float* bias = (const float*)d_in[2];
  float* out     = (float*)d_out;
  float* wtbuf   = (float*)d_ws;
  float* logitsT = (float*)d_ws + WS_WT_FLOATS;

  k_padw  <<<(KP * E_N) / 256, 256, 0, stream>>>(wgt, wtbuf);
  k_logits<<<T_TOK / 128,      512, 0, stream>>>(x, wtbuf, logitsT);
  k_route <<<T_TOK / 256,      256, 0, stream>>>(logitsT, bias,
                                                 out, out + (size_t)T_TOK * 8);
}